// Round 1
// baseline (131.315 us; speedup 1.0000x reference)
//
#include <hip/hip_runtime.h>
#include <hip/hip_fp16.h>

typedef _Float16 half8 __attribute__((ext_vector_type(8)));
typedef __attribute__((ext_vector_type(4))) float f32x4;

#define OUT_ELEMS 8388608

// ws layout (bytes):
// 0      counts int[1024]        (zeroed by prep block 0)
// 4096   loss   float            (zeroed by prep)
// 8192   sq     float[1024]
// 16384  chs    ushort[1024*256] (fp16 of 1024*cb, TILED+SWIZZLED layout, see below)
// 540672 codeG  int[32768]
//
// chs layout (ushorts): [stage s:16][group g:4][chunk:512][8]
//   code = g*256 + s*16 + m; logical 16B chunk j (d = j*8, j=0..31) of code m
//   is stored at chunk position  m*32 + (j ^ (m&7))   (XOR swizzle).
// Rationale: argmin stages each 32KB stage-block LINEARLY into LDS via
// global_load_lds (linear dest required), and reads B-frags with the same
// XOR on the address -> conflict-free ds_read_b128 (8-phase floor).

// ---- prep: zero accumulators + codebook -> fp16*1024 (tiled/swizzled) + ||c||^2 ----
__global__ __launch_bounds__(256) void prep_kernel(const float* __restrict__ cb,
        unsigned short* __restrict__ chs, float* __restrict__ sq,
        int* __restrict__ counts, float* __restrict__ loss) {
    const int t = threadIdx.x;
    if (blockIdx.x == 0) {
        ((int4*)counts)[t] = make_int4(0, 0, 0, 0);
        if (t == 0) *loss = 0.f;
    }
    const int row = blockIdx.x * 16 + (t >> 4);   // code index 0..1023
    const int d0 = (t & 15) * 16;
    const float* src = cb + row * 256 + d0;
    half8 h0, h1;
    float s = 0.f;
#pragma unroll
    for (int i = 0; i < 16; ++i) {
        const float v = src[i];
        s += v * v;
        const _Float16 h = (_Float16)(v * 1024.f);
        if (i < 8) h0[i] = h; else h1[i - 8] = h;
    }
    const int g = row >> 8, sidx = (row >> 4) & 15, m = row & 15, e = m & 7;
    const int j0 = (t & 15) * 2;                  // two 16B chunks per thread
    unsigned short* tile = chs + sidx * 16384 + g * 4096 + m * 256;
    *(half8*)(tile + (((j0    ) ^ e) << 3)) = h0;
    *(half8*)(tile + (((j0 + 1) ^ e) << 3)) = h1;
#pragma unroll
    for (int off = 1; off < 16; off <<= 1) s += __shfl_xor(s, off);
    if ((t & 15) == 0) sq[row] = s;
}

// ---- argmin: grid 256 (1/CU), 512 thr = 8 waves.
// Wave w: code group wg = w>>1 (256 codes), row group wl = w&1 (64 rows, M=64).
// 4 A-frags share each B ds_read_b128 -> MFMA:LDS = 4:1 (was 2:1); B staged
// async via global_load_lds (no staging VGPRs/VALU), double-buffered.
__global__ __launch_bounds__(512, 2) void argmin_kernel(
    const float* __restrict__ x, const unsigned short* __restrict__ chs,
    const float* __restrict__ sq, int* __restrict__ codeG,
    int* __restrict__ counts, float* __restrict__ loss_accum)
{
    __shared__ __align__(16) unsigned char Bs[2][32768];  // 64 KB dbuf
    __shared__ float mv[4][128];
    __shared__ int   mk[4][128];
    __shared__ float xsqL[128];
    __shared__ float wsum[2];

    const int t = threadIdx.x;
    const int lane = t & 63;
    const int w  = t >> 6;
    const int wg = w >> 1;            // code group 0..3
    const int wl = w & 1;             // row group 0..1
    const int m = lane & 15;
    const int q = lane >> 4;
    const int kb = wg << 8;
    const int bid = blockIdx.x;
    const int batch = bid >> 3;
    const int rowb = wl << 6;
    const int hwb = (bid & 7) << 7;
    const float* xb = x + (size_t)batch * 262144 + hwb + rowb + m;

    const char* chsB = (const char*)chs;
    char* bsB = (char*)&Bs[0][0];
    const int stoff = w * 4096 + lane * 16;   // this wave's linear slice of a stage block

    // stage 0 -> buf 0 (async, lands before first barrier's vmcnt drain)
    {
        const char* src = chsB + stoff;
        char* dst = bsB + w * 4096;           // wave-uniform LDS base
#pragma unroll
        for (int i = 0; i < 4; ++i)
            __builtin_amdgcn_global_load_lds(
                (const __attribute__((address_space(1))) void*)(src + i * 1024),
                (__attribute__((address_space(3))) void*)(dst + i * 1024), 16, 0, 0);
    }

    // A prologue: 64 rows/wave, full D=256 -> fp16 frags; fused ||x||^2
    half8 Ah[4][8];
#pragma unroll
    for (int f = 0; f < 4; ++f) {
        float xs = 0.f;
#pragma unroll
        for (int ks = 0; ks < 8; ++ks) {
            half8 a;
#pragma unroll
            for (int j = 0; j < 8; ++j) {
                const float v = xb[f * 16 + ((size_t)(ks * 32 + q * 8 + j) << 10)];
                xs += v * v;
                a[j] = (_Float16)v;
            }
            Ah[f][ks] = a;
        }
        xs += __shfl_xor(xs, 16);
        xs += __shfl_xor(xs, 32);
        if (wg == 0 && q == 0) xsqL[rowb + f * 16 + m] = xs;
    }

    float bestv[4][4];
    int   bestk[4][4];
#pragma unroll
    for (int f = 0; f < 4; ++f)
#pragma unroll
        for (int r = 0; r < 4; ++r) { bestv[f][r] = 3.4e38f; bestk[f][r] = 0; }

    float sc2 = sq[kb + m];           // stage-0 ||c||^2, prefetched

    // swizzled B read base: byte = wg*8192 + m*512 + ((q^(m&3))<<4) + ((ks^((m>>2)&1))<<6)
    const int rbase = wg * 8192 + m * 512 + ((q ^ (m & 3)) << 4);
    const int eh = (m >> 2) & 1;

    for (int s = 0; s < 16; ++s) {
        const int buf = s & 1;
        __syncthreads();              // buf ready (vmcnt drained); buf^1 free to overwrite
        if (s + 1 < 16) {             // async prefetch next stage into buf^1
            const char* src = chsB + (s + 1) * 32768 + stoff;
            char* dst = bsB + (buf ^ 1) * 32768 + w * 4096;
#pragma unroll
            for (int i = 0; i < 4; ++i)
                __builtin_amdgcn_global_load_lds(
                    (const __attribute__((address_space(1))) void*)(src + i * 1024),
                    (__attribute__((address_space(3))) void*)(dst + i * 1024), 16, 0, 0);
        }
        float sc2n = 0.f;
        if (s + 1 < 16) sc2n = sq[kb + (s + 1) * 16 + m];

        f32x4 a0 = {0.f,0.f,0.f,0.f}, a1 = {0.f,0.f,0.f,0.f};
        f32x4 a2 = {0.f,0.f,0.f,0.f}, a3 = {0.f,0.f,0.f,0.f};
        const char* bp = bsB + buf * 32768 + rbase;
#pragma unroll
        for (int ks = 0; ks < 8; ++ks) {
            const half8 b = *(const half8*)(bp + ((ks ^ eh) << 6));
            a0 = __builtin_amdgcn_mfma_f32_16x16x32_f16(Ah[0][ks], b, a0, 0, 0, 0);
            a1 = __builtin_amdgcn_mfma_f32_16x16x32_f16(Ah[1][ks], b, a1, 0, 0, 0);
            a2 = __builtin_amdgcn_mfma_f32_16x16x32_f16(Ah[2][ks], b, a2, 0, 0, 0);
            a3 = __builtin_amdgcn_mfma_f32_16x16x32_f16(Ah[3][ks], b, a3, 0, 0, 0);
        }
        const int code = kb + s * 16 + m;
#pragma unroll
        for (int f = 0; f < 4; ++f) {
            const f32x4 a = (f == 0) ? a0 : (f == 1) ? a1 : (f == 2) ? a2 : a3;
#pragma unroll
            for (int r = 0; r < 4; ++r) {
                const float d0v = fmaf(-0.001953125f, a[r], sc2);  // -2/1024 undoes B scale
                if (d0v < bestv[f][r]) { bestv[f][r] = d0v; bestk[f][r] = code; }
            }
        }
        sc2 = sc2n;
    }

    // per-row argmin across the 16 code-classes; tie -> lower k
#pragma unroll
    for (int f = 0; f < 4; ++f)
#pragma unroll
        for (int r = 0; r < 4; ++r) {
            float v = bestv[f][r];
            int   k = bestk[f][r];
#pragma unroll
            for (int d = 1; d < 16; d <<= 1) {
                const float ov = __shfl_xor(v, d);
                const int   ok = __shfl_xor(k, d);
                if (ov < v || (ov == v && ok < k)) { v = ov; k = ok; }
            }
            if (m == 0) {
                const int row = rowb + f * 16 + q * 4 + r;
                mv[wg][row] = v;
                mk[wg][row] = k;
            }
        }
    __syncthreads();

    // merge the four code-groups (ascending g = ascending codes, strict < keeps lower), hist + loss
    if (t < 128) {
        float v = mv[0][t]; int k = mk[0][t];
#pragma unroll
        for (int g2 = 1; g2 < 4; ++g2) {
            const float vg = mv[g2][t];
            const int   kg = mk[g2][t];
            if (vg < v) { v = vg; k = kg; }
        }
        codeG[bid * 128 + t] = k;
        atomicAdd(&counts[k], 1);
        float lp = xsqL[t] + v;       // ||x - c||^2
#pragma unroll
        for (int off = 32; off > 0; off >>= 1) lp += __shfl_down(lp, off);
        if ((t & 63) == 0) wsum[t >> 6] = lp;
    }
    __syncthreads();
    if (t == 0) atomicAdd(loss_accum, wsum[0] + wsum[1]);
}

// ---- gather: LDS transpose of 64 selected cb rows -> coalesced float4 out ----
__global__ __launch_bounds__(256) void gather_kernel(
    const float* __restrict__ cb, const int* __restrict__ codeG,
    const int* __restrict__ counts, const float* __restrict__ loss_accum,
    float* __restrict__ out)
{
    __shared__ float Q[64][257];
    __shared__ int codeL[64];
    __shared__ float wsum[4];
    const int t = threadIdx.x;
    const int bid = blockIdx.x;
    if (t < 64) codeL[t] = codeG[bid * 64 + t];
    __syncthreads();
    {   // stage: lane -> row r (2-way LDS write = free; global reads L2-hot)
        const int r = t & 63, seg = t >> 6;
        const float* src = cb + (size_t)codeL[r] * 256 + seg * 64;
#pragma unroll
        for (int i = 0; i < 16; ++i)
            *(float4*)&Q[r][seg * 64 + i * 4] = *(const float4*)(src + i * 4);
    }
    __syncthreads();
    const int batch = bid >> 4;
    const int hw0 = (bid & 15) << 6;
    const int hw4 = (t & 15) * 4;
    const int c0 = t >> 4;
    float* dst = out + (size_t)batch * 262144 + hw0 + hw4;
#pragma unroll
    for (int i = 0; i < 16; ++i) {
        const int c = c0 + i * 16;
        float4 v;
        v.x = Q[hw4 + 0][c];
        v.y = Q[hw4 + 1][c];
        v.z = Q[hw4 + 2][c];
        v.w = Q[hw4 + 3][c];
        *(float4*)(dst + (size_t)c * 1024) = v;   // 256B contiguous per 16 lanes
    }
    if (bid == 0) {   // finalize: counts/loss complete (kernel boundary ordering)
        float s = 0.f;
#pragma unroll
        for (int mm = 0; mm < 4; ++mm) {
            const float p = (float)counts[t + 256 * mm] * (1.f / 32768.f);
            s += p * logf(p + 1e-10f);
        }
#pragma unroll
        for (int off = 32; off > 0; off >>= 1) s += __shfl_down(s, off);
        if ((t & 63) == 0) wsum[t >> 6] = s;
        __syncthreads();
        if (t == 0) {
            out[OUT_ELEMS]     = loss_accum[0] * (1.25f / 8388608.f);
            out[OUT_ELEMS + 1] = expf(-(wsum[0] + wsum[1] + wsum[2] + wsum[3]));
        }
    }
}

extern "C" void kernel_launch(void* const* d_in, const int* in_sizes, int n_in,
                              void* d_out, int out_size, void* d_ws, size_t ws_size,
                              hipStream_t stream) {
    const float* x  = (const float*)d_in[0];
    const float* cb = (const float*)d_in[1];
    float* out = (float*)d_out;
    char* wsb = (char*)d_ws;
    int*            counts = (int*)(wsb + 0);
    float*          loss   = (float*)(wsb + 4096);
    float*          sq     = (float*)(wsb + 8192);
    unsigned short* chs    = (unsigned short*)(wsb + 16384);
    int*            codeG  = (int*)(wsb + 540672);

    prep_kernel<<<64, 256, 0, stream>>>(cb, chs, sq, counts, loss);
    argmin_kernel<<<256, 512, 0, stream>>>(x, chs, sq, codeG, counts, loss);
    gather_kernel<<<512, 256, 0, stream>>>(cb, codeG, counts, loss, out);
}

// Round 2
// 126.733 us; speedup vs baseline: 1.0362x; 1.0362x over previous
//
#include <hip/hip_runtime.h>
#include <hip/hip_fp16.h>

typedef _Float16 half8 __attribute__((ext_vector_type(8)));
typedef _Float16 half4v __attribute__((ext_vector_type(4)));
typedef __attribute__((ext_vector_type(4))) float f32x4;

#define OUT_ELEMS 8388608

// ws layout (bytes):
// 0      counts int[1024]        (zeroed by prep block 0)
// 4096   loss   float            (zeroed by prep)
// 8192   sq     float[1024]
// 16384  chs    ushort[1024*256] (fp16 of 1024*cb, TILED+SWIZZLED layout, see below)
// 540672 codeG  int[32768]
//
// chs layout (ushorts): [stage s:16][group g:4][chunk:512][8]
//   code = g*256 + s*16 + m; logical 16B chunk j (d = j*8, j=0..31) of code m
//   is stored at chunk position  m*32 + (j ^ (m&7))   (XOR swizzle).
// argmin stages each 32KB stage-block LINEARLY into LDS via global_load_lds
// (linear dest required) and reads B-frags with the same XOR -> conflict-free.

// ---- prep: zero accumulators + codebook -> fp16*1024 (tiled/swizzled) + ||c||^2 ----
__global__ __launch_bounds__(256) void prep_kernel(const float* __restrict__ cb,
        unsigned short* __restrict__ chs, float* __restrict__ sq,
        int* __restrict__ counts, float* __restrict__ loss) {
    const int t = threadIdx.x;
    if (blockIdx.x == 0) {
        ((int4*)counts)[t] = make_int4(0, 0, 0, 0);
        if (t == 0) *loss = 0.f;
    }
    const int row = blockIdx.x * 16 + (t >> 4);   // code index 0..1023
    const int d0 = (t & 15) * 16;
    const float* src = cb + row * 256 + d0;
    half8 h0, h1;
    float s = 0.f;
#pragma unroll
    for (int i = 0; i < 16; ++i) {
        const float v = src[i];
        s += v * v;
        const _Float16 h = (_Float16)(v * 1024.f);
        if (i < 8) h0[i] = h; else h1[i - 8] = h;
    }
    const int g = row >> 8, sidx = (row >> 4) & 15, m = row & 15, e = m & 7;
    const int j0 = (t & 15) * 2;                  // two 16B chunks per thread
    unsigned short* tile = chs + sidx * 16384 + g * 4096 + m * 256;
    *(half8*)(tile + (((j0    ) ^ e) << 3)) = h0;
    *(half8*)(tile + (((j0 + 1) ^ e) << 3)) = h1;
#pragma unroll
    for (int off = 1; off < 16; off <<= 1) s += __shfl_xor(s, off);
    if ((t & 15) == 0) sq[row] = s;
}

// ---- argmin: grid 256 (1/CU), 512 thr = 8 waves.
// Wave w: code group wg = w>>1 (256 codes), row group wl = w&1 (64 rows, M=64).
// x is staged ONCE through LDS (coalesced float4 -> fp16 [hw][c] swizzled),
// A-frags built via conflict-free ds_read_b128; the same 64KB LDS arena is
// then reused as the B double-buffer (global_load_lds staged, swizzled).
__global__ __launch_bounds__(512, 2) void argmin_kernel(
    const float* __restrict__ x, const unsigned short* __restrict__ chs,
    const float* __restrict__ sq, int* __restrict__ codeG,
    int* __restrict__ counts, float* __restrict__ loss_accum)
{
    __shared__ __align__(16) unsigned char Arena[65536];  // x fp16 staging, then B dbuf [2][32768]
    __shared__ float mv[4][128];
    __shared__ int   mk[4][128];
    __shared__ float xsqL[128];
    __shared__ float wsum[2];

    const int t = threadIdx.x;
    const int lane = t & 63;
    const int w  = t >> 6;
    const int wg = w >> 1;            // code group 0..3
    const int wl = w & 1;             // row group 0..1
    const int m = lane & 15;
    const int q = lane >> 4;
    const int kb = wg << 8;
    const int bid = blockIdx.x;
    const int batch = bid >> 3;
    const int rowb = wl << 6;
    const int hwb = (bid & 7) << 7;

    // ---- x staging: fp32 [c][hw] (global, coalesced) -> fp16 [hw:128][c:256] LDS.
    // 8B-group swizzle: group c4 (4 halfwords) stored at c4 ^ ((hw&7)<<1) (even XOR
    // keeps 16B read-pairs contiguous & aligned).
    unsigned short* XL = (unsigned short*)Arena;
    {
        const float* xg = x + (size_t)batch * 262144 + hwb;
#pragma unroll
        for (int p = 0; p < 4; ++p) {
            const int id = p * 512 + t;
            const int c4 = id >> 5, hw4 = id & 31;
            const float* s0 = xg + (size_t)(c4 * 4) * 1024 + hw4 * 4;
            const f32x4 v0 = *(const f32x4*)(s0);
            const f32x4 v1 = *(const f32x4*)(s0 + 1024);
            const f32x4 v2 = *(const f32x4*)(s0 + 2048);
            const f32x4 v3 = *(const f32x4*)(s0 + 3072);
#pragma unroll
            for (int j = 0; j < 4; ++j) {
                const int hw = hw4 * 4 + j;
                half4v hv;
                hv[0] = (_Float16)v0[j];
                hv[1] = (_Float16)v1[j];
                hv[2] = (_Float16)v2[j];
                hv[3] = (_Float16)v3[j];
                *(half4v*)(XL + hw * 256 + ((c4 ^ ((hw & 7) << 1)) << 2)) = hv;
            }
        }
    }
    __syncthreads();

    // ---- A frags from LDS (aligned b128, conflict-free); fused ||x||^2 (fp16 path)
    half8 Ah[4][8];
#pragma unroll
    for (int f = 0; f < 4; ++f) {
        const int hw = rowb + f * 16 + m;
        const unsigned short* row = XL + hw * 256;
        const int e = (hw & 7) << 1;
        float xs = 0.f;
#pragma unroll
        for (int ks = 0; ks < 8; ++ks) {
            const half8 a = *(const half8*)(row + (((8 * ks + 2 * q) ^ e) << 2));
            Ah[f][ks] = a;
#pragma unroll
            for (int j = 0; j < 8; ++j) { const float fv = (float)a[j]; xs = fmaf(fv, fv, xs); }
        }
        xs += __shfl_xor(xs, 16);
        xs += __shfl_xor(xs, 32);
        if (wg == 0 && q == 0) xsqL[rowb + f * 16 + m] = xs;
    }
    __syncthreads();                  // all frag reads done; Arena becomes B dbuf

    const char* chsB = (const char*)chs;
    char* bsB = (char*)Arena;
    const int stoff = w * 4096 + lane * 16;   // this wave's linear slice of a stage block

    // stage 0 -> buf 0 (async; first loop barrier's vmcnt drain covers it)
    {
        const char* src = chsB + stoff;
        char* dst = bsB + w * 4096;           // wave-uniform LDS base
#pragma unroll
        for (int i = 0; i < 4; ++i)
            __builtin_amdgcn_global_load_lds(
                (const __attribute__((address_space(1))) void*)(src + i * 1024),
                (__attribute__((address_space(3))) void*)(dst + i * 1024), 16, 0, 0);
    }

    float bestv[4][4];
    int   bestk[4][4];
#pragma unroll
    for (int f = 0; f < 4; ++f)
#pragma unroll
        for (int r = 0; r < 4; ++r) { bestv[f][r] = 3.4e38f; bestk[f][r] = 0; }

    float sc2 = sq[kb + m];           // stage-0 ||c||^2, prefetched

    // swizzled B read base
    const int rbase = wg * 8192 + m * 512 + ((q ^ (m & 3)) << 4);
    const int eh = (m >> 2) & 1;

    for (int s = 0; s < 16; ++s) {
        const int buf = s & 1;
        __syncthreads();              // buf ready (vmcnt drained); buf^1 free to overwrite
        if (s + 1 < 16) {             // async prefetch next stage into buf^1
            const char* src = chsB + (s + 1) * 32768 + stoff;
            char* dst = bsB + (buf ^ 1) * 32768 + w * 4096;
#pragma unroll
            for (int i = 0; i < 4; ++i)
                __builtin_amdgcn_global_load_lds(
                    (const __attribute__((address_space(1))) void*)(src + i * 1024),
                    (__attribute__((address_space(3))) void*)(dst + i * 1024), 16, 0, 0);
        }
        float sc2n = 0.f;
        if (s + 1 < 16) sc2n = sq[kb + (s + 1) * 16 + m];

        f32x4 a0 = {0.f,0.f,0.f,0.f}, a1 = {0.f,0.f,0.f,0.f};
        f32x4 a2 = {0.f,0.f,0.f,0.f}, a3 = {0.f,0.f,0.f,0.f};
        const char* bp = bsB + buf * 32768 + rbase;
#pragma unroll
        for (int ks = 0; ks < 8; ++ks) {
            const half8 b = *(const half8*)(bp + ((ks ^ eh) << 6));
            a0 = __builtin_amdgcn_mfma_f32_16x16x32_f16(Ah[0][ks], b, a0, 0, 0, 0);
            a1 = __builtin_amdgcn_mfma_f32_16x16x32_f16(Ah[1][ks], b, a1, 0, 0, 0);
            a2 = __builtin_amdgcn_mfma_f32_16x16x32_f16(Ah[2][ks], b, a2, 0, 0, 0);
            a3 = __builtin_amdgcn_mfma_f32_16x16x32_f16(Ah[3][ks], b, a3, 0, 0, 0);
        }
        const int code = kb + s * 16 + m;
#pragma unroll
        for (int f = 0; f < 4; ++f) {
            const f32x4 a = (f == 0) ? a0 : (f == 1) ? a1 : (f == 2) ? a2 : a3;
#pragma unroll
            for (int r = 0; r < 4; ++r) {
                const float d0v = fmaf(-0.001953125f, a[r], sc2);  // -2/1024 undoes B scale
                if (d0v < bestv[f][r]) { bestv[f][r] = d0v; bestk[f][r] = code; }
            }
        }
        sc2 = sc2n;
    }

    // per-row argmin across the 16 code-classes; tie -> lower k
#pragma unroll
    for (int f = 0; f < 4; ++f)
#pragma unroll
        for (int r = 0; r < 4; ++r) {
            float v = bestv[f][r];
            int   k = bestk[f][r];
#pragma unroll
            for (int d = 1; d < 16; d <<= 1) {
                const float ov = __shfl_xor(v, d);
                const int   ok = __shfl_xor(k, d);
                if (ov < v || (ov == v && ok < k)) { v = ov; k = ok; }
            }
            if (m == 0) {
                const int row = rowb + f * 16 + q * 4 + r;
                mv[wg][row] = v;
                mk[wg][row] = k;
            }
        }
    __syncthreads();

    // merge the four code-groups (ascending g, strict < keeps lower code), hist + loss
    if (t < 128) {
        float v = mv[0][t]; int k = mk[0][t];
#pragma unroll
        for (int g2 = 1; g2 < 4; ++g2) {
            const float vg = mv[g2][t];
            const int   kg = mk[g2][t];
            if (vg < v) { v = vg; k = kg; }
        }
        codeG[bid * 128 + t] = k;
        atomicAdd(&counts[k], 1);
        float lp = xsqL[t] + v;       // ||x - c||^2
#pragma unroll
        for (int off = 32; off > 0; off >>= 1) lp += __shfl_down(lp, off);
        if ((t & 63) == 0) wsum[t >> 6] = lp;
    }
    __syncthreads();
    if (t == 0) atomicAdd(loss_accum, wsum[0] + wsum[1]);
}

// ---- gather: LDS transpose of 64 selected cb rows -> coalesced float4 out ----
__global__ __launch_bounds__(256) void gather_kernel(
    const float* __restrict__ cb, const int* __restrict__ codeG,
    const int* __restrict__ counts, const float* __restrict__ loss_accum,
    float* __restrict__ out)
{
    __shared__ float Q[64][257];
    __shared__ int codeL[64];
    __shared__ float wsum[4];
    const int t = threadIdx.x;
    const int bid = blockIdx.x;
    if (t < 64) codeL[t] = codeG[bid * 64 + t];
    __syncthreads();
    {   // stage: lane -> row r (2-way LDS write = free; global reads L2-hot)
        const int r = t & 63, seg = t >> 6;
        const float* src = cb + (size_t)codeL[r] * 256 + seg * 64;
#pragma unroll
        for (int i = 0; i < 16; ++i)
            *(float4*)&Q[r][seg * 64 + i * 4] = *(const float4*)(src + i * 4);
    }
    __syncthreads();
    const int batch = bid >> 4;
    const int hw0 = (bid & 15) << 6;
    const int hw4 = (t & 15) * 4;
    const int c0 = t >> 4;
    float* dst = out + (size_t)batch * 262144 + hw0 + hw4;
#pragma unroll
    for (int i = 0; i < 16; ++i) {
        const int c = c0 + i * 16;
        float4 v;
        v.x = Q[hw4 + 0][c];
        v.y = Q[hw4 + 1][c];
        v.z = Q[hw4 + 2][c];
        v.w = Q[hw4 + 3][c];
        *(float4*)(dst + (size_t)c * 1024) = v;   // 256B contiguous per 16 lanes
    }
    if (bid == 0) {   // finalize: counts/loss complete (kernel boundary ordering)
        float s = 0.f;
#pragma unroll
        for (int mm = 0; mm < 4; ++mm) {
            const float p = (float)counts[t + 256 * mm] * (1.f / 32768.f);
            s += p * logf(p + 1e-10f);
        }
#pragma unroll
        for (int off = 32; off > 0; off >>= 1) s += __shfl_down(s, off);
        if ((t & 63) == 0) wsum[t >> 6] = s;
        __syncthreads();
        if (t == 0) {
            out[OUT_ELEMS]     = loss_accum[0] * (1.25f / 8388608.f);
            out[OUT_ELEMS + 1] = expf(-(wsum[0] + wsum[1] + wsum[2] + wsum[3]));
        }
    }
}

extern "C" void kernel_launch(void* const* d_in, const int* in_sizes, int n_in,
                              void* d_out, int out_size, void* d_ws, size_t ws_size,
                              hipStream_t stream) {
    const float* x  = (const float*)d_in[0];
    const float* cb = (const float*)d_in[1];
    float* out = (float*)d_out;
    char* wsb = (char*)d_ws;
    int*            counts = (int*)(wsb + 0);
    float*          loss   = (float*)(wsb + 4096);
    float*          sq     = (float*)(wsb + 8192);
    unsigned short* chs    = (unsigned short*)(wsb + 16384);
    int*            codeG  = (int*)(wsb + 540672);

    prep_kernel<<<64, 256, 0, stream>>>(cb, chs, sq, counts, loss);
    argmin_kernel<<<256, 512, 0, stream>>>(x, chs, sq, codeG, counts, loss);
    gather_kernel<<<512, 256, 0, stream>>>(cb, codeG, counts, loss, out);
}

// Round 3
// 121.867 us; speedup vs baseline: 1.0775x; 1.0399x over previous
//
#include <hip/hip_runtime.h>
#include <hip/hip_fp16.h>

typedef _Float16 half8 __attribute__((ext_vector_type(8)));
typedef _Float16 half4v __attribute__((ext_vector_type(4)));
typedef __attribute__((ext_vector_type(4))) float f32x4;

#define OUT_ELEMS 8388608

// ws layout (bytes):
// 0      counts int[1024]        (zeroed by prep block 0)
// 4096   loss   float            (zeroed by prep)
// 8192   sq     float[1024]
// 16384  chs    ushort[1024*256] (fp16 of 1024*cb, TILED+SWIZZLED, see below)
//
// chs layout (ushorts): [stage s:16][group g:4][chunk:512][8]
//   code = g*256 + s*16 + m; logical 16B chunk j (d = j*8, j=0..31) of code m
//   is stored at chunk position  m*32 + (j ^ (m&7))   (XOR swizzle).
// vq stages each 32KB stage-block LINEARLY into LDS via global_load_lds
// (linear dest required) and reads B-frags with the same XOR -> conflict-free.

// ---- prep: zero accumulators + codebook -> fp16*1024 (tiled/swizzled) + ||c||^2 ----
__global__ __launch_bounds__(256) void prep_kernel(const float* __restrict__ cb,
        unsigned short* __restrict__ chs, float* __restrict__ sq,
        int* __restrict__ counts, float* __restrict__ loss) {
    const int t = threadIdx.x;
    if (blockIdx.x == 0) {
        ((int4*)counts)[t] = make_int4(0, 0, 0, 0);
        if (t == 0) *loss = 0.f;
    }
    const int row = blockIdx.x * 16 + (t >> 4);   // code index 0..1023
    const int d0 = (t & 15) * 16;
    const float* src = cb + row * 256 + d0;
    half8 h0, h1;
    float s = 0.f;
#pragma unroll
    for (int i = 0; i < 16; ++i) {
        const float v = src[i];
        s += v * v;
        const _Float16 h = (_Float16)(v * 1024.f);
        if (i < 8) h0[i] = h; else h1[i - 8] = h;
    }
    const int g = row >> 8, sidx = (row >> 4) & 15, m = row & 15, e = m & 7;
    const int j0 = (t & 15) * 2;                  // two 16B chunks per thread
    unsigned short* tile = chs + sidx * 16384 + g * 4096 + m * 256;
    *(half8*)(tile + (((j0    ) ^ e) << 3)) = h0;
    *(half8*)(tile + (((j0 + 1) ^ e) << 3)) = h1;
#pragma unroll
    for (int off = 1; off < 16; off <<= 1) s += __shfl_xor(s, off);
    if ((t & 15) == 0) sq[row] = s;
}

// ---- fused vq: grid 512 (2/CU), 256 thr = 4 waves (one per code group), M=64.
// Phases: x->LDS fp16 (swizzled) | A-frags | 16-stage B loop (gload_lds dbuf)
// | merge/hist/loss | gather (LDS fp32 transpose, 2 halves) -> out.
__global__ __launch_bounds__(256, 2) void vq_kernel(
    const float* __restrict__ x, const float* __restrict__ cb,
    const unsigned short* __restrict__ chs, const float* __restrict__ sq,
    int* __restrict__ counts, float* __restrict__ loss_accum,
    float* __restrict__ out)
{
    __shared__ __align__(16) unsigned char Arena[65536]; // XL(32K) -> B dbuf(64K) -> Q(33K)
    __shared__ float mv[4][64];
    __shared__ int   mk[4][64];
    __shared__ float xsqL[64];
    __shared__ int   codeL[64];

    const int t = threadIdx.x;
    const int lane = t & 63;
    const int w = t >> 6;             // 0..3 = code group
    const int m = lane & 15;
    const int q = lane >> 4;
    const int kb = w << 8;
    const int bid = blockIdx.x;
    const int batch = bid >> 4;
    const int hwb = (bid & 15) << 6;  // 64 hw rows per block

    // ---- x staging: fp32 [c][hw] (coalesced) -> fp16 [hw:64][c:256] LDS.
    // 8B-group swizzle e(hw) = ((hw&7) ^ ((hw>>3)&7)) << 1  (even -> 16B reads
    // stay contiguous; varies under BOTH stride-4 write and consecutive read).
    unsigned short* XL = (unsigned short*)Arena;
    {
        const float* xg = x + (size_t)batch * 262144 + hwb;
#pragma unroll
        for (int p = 0; p < 4; ++p) {
            const int id = p * 256 + t;
            const int c4 = id >> 4;       // 0..63 (c-group of 4)
            const int hw4 = id & 15;      // 0..15 (hw-group of 4)
            const float* s0 = xg + (size_t)(c4 * 4) * 1024 + hw4 * 4;
            const f32x4 v0 = *(const f32x4*)(s0);
            const f32x4 v1 = *(const f32x4*)(s0 + 1024);
            const f32x4 v2 = *(const f32x4*)(s0 + 2048);
            const f32x4 v3 = *(const f32x4*)(s0 + 3072);
#pragma unroll
            for (int j = 0; j < 4; ++j) {
                const int hw = hw4 * 4 + j;
                const int e = (((hw & 7) ^ ((hw >> 3) & 7)) << 1);
                half4v hv;
                hv[0] = (_Float16)v0[j];
                hv[1] = (_Float16)v1[j];
                hv[2] = (_Float16)v2[j];
                hv[3] = (_Float16)v3[j];
                *(half4v*)(XL + hw * 256 + ((c4 ^ e) << 2)) = hv;
            }
        }
    }
    __syncthreads();

    const char* chsB = (const char*)chs;
    char* bsB = (char*)Arena;
    const int so = w * 8192 + lane * 16;  // wave's linear slice of a 32KB stage

    // stage 0 -> buf1 (bytes 32768..65536: does NOT overlap XL) so the A-frag
    // build below hides its L2 latency.
    {
        const char* src = chsB + so;
        char* dst = bsB + 32768 + w * 8192;
#pragma unroll
        for (int i = 0; i < 8; ++i)
            __builtin_amdgcn_global_load_lds(
                (const __attribute__((address_space(1))) void*)(src + i * 1024),
                (__attribute__((address_space(3))) void*)(dst + i * 1024), 16, 0, 0);
    }

    // ---- A frags from LDS (conflict-free b128); fused ||x||^2 (fp16 path)
    half8 Ah[4][8];
#pragma unroll
    for (int f = 0; f < 4; ++f) {
        const int hw = f * 16 + m;
        const unsigned short* row = XL + hw * 256;
        const int e = (((hw & 7) ^ ((hw >> 3) & 7)) << 1);
        float xs = 0.f;
#pragma unroll
        for (int ks = 0; ks < 8; ++ks) {
            const half8 a = *(const half8*)(row + (((8 * ks + 2 * q) ^ e) << 2));
            Ah[f][ks] = a;
#pragma unroll
            for (int j = 0; j < 8; ++j) { const float fv = (float)a[j]; xs = fmaf(fv, fv, xs); }
        }
        xs += __shfl_xor(xs, 16);
        xs += __shfl_xor(xs, 32);
        if (w == 0 && q == 0) xsqL[hw] = xs;
    }
    __syncthreads();                  // XL dead; arena is now the B double-buffer

    float bestv[4][4];
    int   bestk[4][4];
#pragma unroll
    for (int f = 0; f < 4; ++f)
#pragma unroll
        for (int r = 0; r < 4; ++r) { bestv[f][r] = 3.4e38f; bestk[f][r] = 0; }

    float sc2 = sq[kb + m];           // stage-0 ||c||^2, prefetched

    const int rbase = w * 8192 + m * 512 + ((q ^ (m & 3)) << 4);
    const int eh = (m >> 2) & 1;

    for (int s = 0; s < 16; ++s) {
        const int buf = (s + 1) & 1;  // stage0 lives in buf1
        __syncthreads();              // buf ready (vmcnt drained); buf^1 free
        if (s + 1 < 16) {             // async prefetch next stage into buf^1
            const char* src = chsB + (s + 1) * 32768 + so;
            char* dst = bsB + (buf ^ 1) * 32768 + w * 8192;
#pragma unroll
            for (int i = 0; i < 8; ++i)
                __builtin_amdgcn_global_load_lds(
                    (const __attribute__((address_space(1))) void*)(src + i * 1024),
                    (__attribute__((address_space(3))) void*)(dst + i * 1024), 16, 0, 0);
        }
        float sc2n = 0.f;
        if (s + 1 < 16) sc2n = sq[kb + (s + 1) * 16 + m];

        f32x4 a0 = {0.f,0.f,0.f,0.f}, a1 = {0.f,0.f,0.f,0.f};
        f32x4 a2 = {0.f,0.f,0.f,0.f}, a3 = {0.f,0.f,0.f,0.f};
        const char* bp = bsB + buf * 32768 + rbase;
#pragma unroll
        for (int ks = 0; ks < 8; ++ks) {
            const half8 b = *(const half8*)(bp + ((ks ^ eh) << 6));
            a0 = __builtin_amdgcn_mfma_f32_16x16x32_f16(Ah[0][ks], b, a0, 0, 0, 0);
            a1 = __builtin_amdgcn_mfma_f32_16x16x32_f16(Ah[1][ks], b, a1, 0, 0, 0);
            a2 = __builtin_amdgcn_mfma_f32_16x16x32_f16(Ah[2][ks], b, a2, 0, 0, 0);
            a3 = __builtin_amdgcn_mfma_f32_16x16x32_f16(Ah[3][ks], b, a3, 0, 0, 0);
        }
        const int code = kb + s * 16 + m;
#pragma unroll
        for (int f = 0; f < 4; ++f) {
            const f32x4 a = (f == 0) ? a0 : (f == 1) ? a1 : (f == 2) ? a2 : a3;
#pragma unroll
            for (int r = 0; r < 4; ++r) {
                const float d0v = fmaf(-0.001953125f, a[r], sc2);  // -2/1024 undoes B scale
                if (d0v < bestv[f][r]) { bestv[f][r] = d0v; bestk[f][r] = code; }
            }
        }
        sc2 = sc2n;
    }

    // per-row argmin across the 16 code-classes; tie -> lower k
#pragma unroll
    for (int f = 0; f < 4; ++f)
#pragma unroll
        for (int r = 0; r < 4; ++r) {
            float v = bestv[f][r];
            int   k = bestk[f][r];
#pragma unroll
            for (int d = 1; d < 16; d <<= 1) {
                const float ov = __shfl_xor(v, d);
                const int   ok = __shfl_xor(k, d);
                if (ov < v || (ov == v && ok < k)) { v = ov; k = ok; }
            }
            if (m == 0) {
                const int row = f * 16 + q * 4 + r;
                mv[w][row] = v;
                mk[w][row] = k;
            }
        }
    __syncthreads();

    // merge 4 code-groups (ascending g, strict < keeps lower code), hist + loss
    if (t < 64) {
        float v = mv[0][t]; int k = mk[0][t];
#pragma unroll
        for (int g2 = 1; g2 < 4; ++g2) {
            const float vg = mv[g2][t];
            const int   kg = mk[g2][t];
            if (vg < v) { v = vg; k = kg; }
        }
        codeL[t] = k;
        atomicAdd(&counts[k], 1);
        float lp = xsqL[t] + v;       // ||x - c||^2
#pragma unroll
        for (int off = 32; off > 0; off >>= 1) lp += __shfl_down(lp, off);
        if (t == 0) atomicAdd(loss_accum, lp);
    }
    __syncthreads();                  // codeL ready; loop's last B reads done

    // ---- fused gather: two 32-row halves through Q[32][257] (fp32, in arena)
    float* Q = (float*)Arena;
#pragma unroll
    for (int h = 0; h < 2; ++h) {
        {   // stage 32 cb rows
            const int r = t & 31, seg = t >> 5;   // 8 segments x 32 c
            const float* src = cb + (size_t)codeL[h * 32 + r] * 256 + seg * 32;
#pragma unroll
            for (int i = 0; i < 8; ++i)
                *(f32x4*)&Q[r * 257 + seg * 32 + i * 4] = *(const f32x4*)(src + i * 4);
        }
        __syncthreads();
        {   // transpose write: 128B-contiguous fp32 runs per c
            const int hw4 = (t & 7) * 4;
            const int c0 = t >> 3;                // 0..31
            float* dst = out + (size_t)batch * 262144 + hwb + h * 32 + hw4;
#pragma unroll
            for (int i = 0; i < 8; ++i) {
                const int c = c0 + i * 32;
                f32x4 v;
                v[0] = Q[(hw4 + 0) * 257 + c];
                v[1] = Q[(hw4 + 1) * 257 + c];
                v[2] = Q[(hw4 + 2) * 257 + c];
                v[3] = Q[(hw4 + 3) * 257 + c];
                *(f32x4*)(dst + (size_t)c * 1024) = v;
            }
        }
        if (h == 0) __syncthreads();  // before overwriting Q for half 1
    }
}

// ---- finalize: perplexity + loss scalar outputs (counts complete: kernel boundary)
__global__ __launch_bounds__(256) void finalize_kernel(
    const int* __restrict__ counts, const float* __restrict__ loss_accum,
    float* __restrict__ out)
{
    __shared__ float wsum[4];
    const int t = threadIdx.x;
    float s = 0.f;
#pragma unroll
    for (int mm = 0; mm < 4; ++mm) {
        const float p = (float)counts[t + 256 * mm] * (1.f / 32768.f);
        s += p * logf(p + 1e-10f);
    }
#pragma unroll
    for (int off = 32; off > 0; off >>= 1) s += __shfl_down(s, off);
    if ((t & 63) == 0) wsum[t >> 6] = s;
    __syncthreads();
    if (t == 0) {
        out[OUT_ELEMS]     = loss_accum[0] * (1.25f / 8388608.f);
        out[OUT_ELEMS + 1] = expf(-(wsum[0] + wsum[1] + wsum[2] + wsum[3]));
    }
}

extern "C" void kernel_launch(void* const* d_in, const int* in_sizes, int n_in,
                              void* d_out, int out_size, void* d_ws, size_t ws_size,
                              hipStream_t stream) {
    const float* x  = (const float*)d_in[0];
    const float* cb = (const float*)d_in[1];
    float* out = (float*)d_out;
    char* wsb = (char*)d_ws;
    int*            counts = (int*)(wsb + 0);
    float*          loss   = (float*)(wsb + 4096);
    float*          sq     = (float*)(wsb + 8192);
    unsigned short* chs    = (unsigned short*)(wsb + 16384);

    prep_kernel<<<64, 256, 0, stream>>>(cb, chs, sq, counts, loss);
    vq_kernel<<<512, 256, 0, stream>>>(x, cb, chs, sq, counts, loss, out);
    finalize_kernel<<<1, 256, 0, stream>>>(counts, loss, out);
}